// Round 3
// baseline (478.486 us; speedup 1.0000x reference)
//
#include <hip/hip_runtime.h>
#include <hip/hip_bf16.h>

#define NROWS 16384
#define DIM   1024
#define NT    (DIM / 64)                 // 16 K-tiles
#define NTILE (NROWS / 256)              // 64 tiles per dim
#define NBLK  (NTILE * (NTILE + 1) / 2)  // 2080 upper-tri blocks

typedef __bf16 bf16x8 __attribute__((ext_vector_type(8)));
typedef __bf16 bf16x4 __attribute__((ext_vector_type(4)));
typedef float  f32x4  __attribute__((ext_vector_type(4)));

// monotone float -> uint key (order-preserving), so atomicMax works on floats
__device__ __forceinline__ unsigned fkey(float f) {
    unsigned u = __float_as_uint(f);
    return (u & 0x80000000u) ? ~u : (u | 0x80000000u);
}
__device__ __forceinline__ float funkey(unsigned k) {
    unsigned u = (k & 0x80000000u) ? (k & 0x7fffffffu) : ~k;
    return __uint_as_float(u);
}

// One block per row: fp32 sum-of-squares, scale, emit bf16 row. Also init rowmax.
__global__ void normalize_rows(const float* __restrict__ x,
                               __hip_bfloat16* __restrict__ xn,
                               unsigned* __restrict__ rowmax) {
    const int row = blockIdx.x;
    const int t = threadIdx.x;                      // 256 threads, 1 float4 each
    const float4 v = ((const float4*)(x + (size_t)row * DIM))[t];
    float ss = v.x * v.x + v.y * v.y + v.z * v.z + v.w * v.w;
#pragma unroll
    for (int off = 32; off > 0; off >>= 1) ss += __shfl_xor(ss, off);
    __shared__ float wss[4];
    if ((t & 63) == 0) wss[t >> 6] = ss;
    __syncthreads();
    const float tot = wss[0] + wss[1] + wss[2] + wss[3];
    const float scale = 1.0f / fmaxf(sqrtf(tot), 1e-12f);
    bf16x4 o;
    o[0] = (__bf16)(v.x * scale);
    o[1] = (__bf16)(v.y * scale);
    o[2] = (__bf16)(v.z * scale);
    o[3] = (__bf16)(v.w * scale);
    *(bf16x4*)(xn + (size_t)row * DIM + t * 4) = o;
    if (t == 0) rowmax[row] = 0u;                   // below fkey of any real sim
}

// 256x256 tile of sim = xn * xn^T, phase-interleaved schedule (T2 swizzle +
// T3/T4 counted vmcnt + T5 setprio). Upper-triangle tiles only; tile reduces
// to per-row and per-col maxes -> atomicMax into rowmax.
__global__ __launch_bounds__(512, 2)
void simmax_kernel(const __hip_bfloat16* __restrict__ xn,
                   unsigned* __restrict__ rowmax) {
    // decode upper-triangle block index -> (it, jt), jt >= it
    int rem = blockIdx.x;
    int it = 0;
    while (rem >= NTILE - it) { rem -= NTILE - it; ++it; }
    const int jt = it + rem;
    const bool diag = (jt == it);
    const int rowBase = it * 256;
    const int colBase = jt * 256;

    __shared__ __hip_bfloat16 lds[2][2][256][64];   // [buf][A/B][row][k] = 128 KiB

    const int t    = threadIdx.x;
    const int lane = t & 63;
    const int wid  = t >> 6;        // 0..7
    const int wr   = wid >> 2;      // 0..1 (M)
    const int wc   = wid & 3;       // 0..3 (N)

    // Staging map: chunk c = l*512 + t  (c<2048: A, else B), row=(c>>3)&255,
    // ch=c&7. LDS dest is LINEAR (c*16 bytes); the SOURCE col is pre-swizzled
    // (ch ^ (row&7)) so the swizzled ds_read below finds its data (rule #21).
    const __hip_bfloat16* srcp[8];
#pragma unroll
    for (int l = 0; l < 8; ++l) {
        const int c   = l * 512 + t;
        const int op  = c >> 11;
        const int row = (c >> 3) & 255;
        const int ch  = c & 7;
        const int gr  = (op ? colBase : rowBase) + row;
        const int gc  = (ch ^ (row & 7)) * 8;
        srcp[l] = xn + (size_t)gr * DIM + gc;
    }

    char* ldsb = (char*)&lds[0][0][0][0];

    // prologue: stage K-tile 0 into buf 0 (8 x 16B per thread)
#pragma unroll
    for (int l = 0; l < 8; ++l) {
        __builtin_amdgcn_global_load_lds(
            (const __attribute__((address_space(1))) void*)srcp[l],
            (__attribute__((address_space(3))) void*)(ldsb + (l * 512 + wid * 64) * 16),
            16, 0, 0);
        srcp[l] += 64;
    }

    f32x4 acc[8][4];
#pragma unroll
    for (int m = 0; m < 8; ++m)
#pragma unroll
        for (int n = 0; n < 4; ++n)
            acc[m][n] = (f32x4){0.f, 0.f, 0.f, 0.f};

    for (int tk = 0; tk < NT; ++tk) {
        const int cur = tk & 1;
        const bool pf = (tk + 1 < NT);
        char* curA = (char*)&lds[cur][0][0][0];
        char* curB = (char*)&lds[cur][1][0][0];
        char* nxtb = (char*)&lds[cur ^ 1][0][0][0];

#pragma unroll
        for (int q = 0; q < 4; ++q) {               // 4 phases per K-tile
            const int qm = q >> 1, qn = q & 1;      // C-quadrant of this phase

            // stage 2 chunks of NEXT tile into the other buffer (safe: dbuf
            // means the buffer being written is never read this tile)
            if (pf) {
#pragma unroll
                for (int j = 0; j < 2; ++j) {
                    const int l = q * 2 + j;
                    __builtin_amdgcn_global_load_lds(
                        (const __attribute__((address_space(1))) void*)srcp[l],
                        (__attribute__((address_space(3))) void*)(nxtb + (l * 512 + wid * 64) * 16),
                        16, 0, 0);
                    srcp[l] += 64;
                }
            }
            if (q == 0) {
                // counted vmcnt: current tile's 8 loads done, the 2 just-issued
                // next-tile loads stay in flight. MUST be followed by a barrier:
                // each wave's vmcnt only covers its OWN global_load_lds writes,
                // but ds_reads below consume rows staged by OTHER waves
                // (round-2 race). __syncthreads() = s_barrier + compiler fence
                // so the ds_reads cannot hoist above it.
                if (pf) asm volatile("s_waitcnt vmcnt(2)" ::: "memory");
                else    asm volatile("s_waitcnt vmcnt(0)" ::: "memory");
                __syncthreads();
            }

            // ds_read this quadrant's fragments (swizzled chunk index)
            bf16x8 af[4][2], bf[2][2];
#pragma unroll
            for (int m2 = 0; m2 < 4; ++m2) {
                const int row = wr * 128 + qm * 64 + m2 * 16 + (lane & 15);
#pragma unroll
                for (int kk = 0; kk < 2; ++kk) {
                    const int chn = (kk * 4 + (lane >> 4)) ^ (row & 7);
                    af[m2][kk] = *(const bf16x8*)(curA + row * 128 + chn * 16);
                }
            }
#pragma unroll
            for (int n2 = 0; n2 < 2; ++n2) {
                const int row = wc * 64 + qn * 32 + n2 * 16 + (lane & 15);
#pragma unroll
                for (int kk = 0; kk < 2; ++kk) {
                    const int chn = (kk * 4 + (lane >> 4)) ^ (row & 7);
                    bf[n2][kk] = *(const bf16x8*)(curB + row * 128 + chn * 16);
                }
            }

            __builtin_amdgcn_s_barrier();
            asm volatile("s_waitcnt lgkmcnt(0)" ::: "memory");
            __builtin_amdgcn_sched_barrier(0);
            __builtin_amdgcn_s_setprio(1);
#pragma unroll
            for (int m2 = 0; m2 < 4; ++m2)
#pragma unroll
                for (int n2 = 0; n2 < 2; ++n2)
#pragma unroll
                    for (int kk = 0; kk < 2; ++kk)
                        acc[qm * 4 + m2][qn * 2 + n2] =
                            __builtin_amdgcn_mfma_f32_16x16x32_bf16(
                                af[m2][kk], bf[n2][kk],
                                acc[qm * 4 + m2][qn * 2 + n2], 0, 0, 0);
            __builtin_amdgcn_s_setprio(0);
            __builtin_amdgcn_s_barrier();
        }
    }

    // ---- epilogue: tile max reduction ----
    // C/D layout: col = lane&15, row = (lane>>4)*4 + reg  [m89/m91]
    const int g  = lane >> 4;
    const int cl = lane & 15;

    if (diag) {                                     // mask self-similarity
#pragma unroll
        for (int m = 0; m < 8; ++m)
#pragma unroll
            for (int n = 0; n < 4; ++n)
#pragma unroll
                for (int r = 0; r < 4; ++r) {
                    const int grow = wr * 128 + m * 16 + g * 4 + r;
                    const int gcol = wc * 64 + n * 16 + cl;
                    if (grow == gcol) acc[m][n][r] = -3.0f;
                }
    }

    // row-direction max (over this tile's cols), reduce over cl lanes
#pragma unroll
    for (int m = 0; m < 8; ++m)
#pragma unroll
        for (int r = 0; r < 4; ++r) {
            float v = fmaxf(fmaxf(acc[m][0][r], acc[m][1][r]),
                            fmaxf(acc[m][2][r], acc[m][3][r]));
            v = fmaxf(v, __shfl_xor(v, 1));
            v = fmaxf(v, __shfl_xor(v, 2));
            v = fmaxf(v, __shfl_xor(v, 4));
            v = fmaxf(v, __shfl_xor(v, 8));
            if (cl == 0) {
                const int grow = rowBase + wr * 128 + m * 16 + g * 4 + r;
                atomicMax(rowmax + grow, fkey(v));
            }
        }

    // col-direction max (transpose contribution), skip on diagonal tiles
    if (!diag) {
#pragma unroll
        for (int n = 0; n < 4; ++n) {
            float v = -3.0f;
#pragma unroll
            for (int m = 0; m < 8; ++m)
#pragma unroll
                for (int r = 0; r < 4; ++r)
                    v = fmaxf(v, acc[m][n][r]);
            v = fmaxf(v, __shfl_xor(v, 16));
            v = fmaxf(v, __shfl_xor(v, 32));
            if (g == 0) {
                const int gcol = colBase + wc * 64 + n * 16 + cl;
                atomicMax(rowmax + gcol, fkey(v));
            }
        }
    }
}

__global__ void finalize_kernel(const unsigned* __restrict__ rowmax,
                                float* __restrict__ out) {
    const int t = threadIdx.x;            // 256 threads, 1 block
    float s = 0.f;
    for (int r = t; r < NROWS; r += 256) {
        const float m = fminf(funkey(rowmax[r]), 1.0f);   // NaN guard
        s += logf(2.0f - 2.0f * m + 1e-8f);
    }
#pragma unroll
    for (int off = 32; off > 0; off >>= 1) s += __shfl_xor(s, off);
    __shared__ float ws[4];
    if ((t & 63) == 0) ws[t >> 6] = s;
    __syncthreads();
    if (t == 0) out[0] = -0.5f * (ws[0] + ws[1] + ws[2] + ws[3]) / (float)NROWS;
}

extern "C" void kernel_launch(void* const* d_in, const int* in_sizes, int n_in,
                              void* d_out, int out_size, void* d_ws, size_t ws_size,
                              hipStream_t stream) {
    const float* x = (const float*)d_in[0];
    __hip_bfloat16* xn = (__hip_bfloat16*)d_ws;
    unsigned* rowmax = (unsigned*)((char*)d_ws + (size_t)NROWS * DIM * sizeof(__hip_bfloat16));
    float* out = (float*)d_out;

    normalize_rows<<<NROWS, 256, 0, stream>>>(x, xn, rowmax);
    simmax_kernel<<<NBLK, 512, 0, stream>>>(xn, rowmax);
    finalize_kernel<<<1, 256, 0, stream>>>(rowmax, out);
}

// Round 4
// 381.724 us; speedup vs baseline: 1.2535x; 1.2535x over previous
//
#include <hip/hip_runtime.h>
#include <hip/hip_bf16.h>

#define NROWS 16384
#define DIM   1024
#define NT    (DIM / 64)                 // 16 K-tiles
#define NTILE (NROWS / 256)              // 64 tiles per dim
#define NBLK  (NTILE * (NTILE + 1) / 2)  // 2080 upper-tri blocks

typedef __bf16 bf16x8 __attribute__((ext_vector_type(8)));
typedef __bf16 bf16x4 __attribute__((ext_vector_type(4)));
typedef float  f32x4  __attribute__((ext_vector_type(4)));

// monotone float -> uint key (order-preserving), so atomicMax works on floats
__device__ __forceinline__ unsigned fkey(float f) {
    unsigned u = __float_as_uint(f);
    return (u & 0x80000000u) ? ~u : (u | 0x80000000u);
}
__device__ __forceinline__ float funkey(unsigned k) {
    unsigned u = (k & 0x80000000u) ? (k & 0x7fffffffu) : ~k;
    return __uint_as_float(u);
}

// One block per row: fp32 sum-of-squares, scale, emit bf16 row. Also init rowmax.
__global__ void normalize_rows(const float* __restrict__ x,
                               __hip_bfloat16* __restrict__ xn,
                               unsigned* __restrict__ rowmax) {
    const int row = blockIdx.x;
    const int t = threadIdx.x;                      // 256 threads, 1 float4 each
    const float4 v = ((const float4*)(x + (size_t)row * DIM))[t];
    float ss = v.x * v.x + v.y * v.y + v.z * v.z + v.w * v.w;
#pragma unroll
    for (int off = 32; off > 0; off >>= 1) ss += __shfl_xor(ss, off);
    __shared__ float wss[4];
    if ((t & 63) == 0) wss[t >> 6] = ss;
    __syncthreads();
    const float tot = wss[0] + wss[1] + wss[2] + wss[3];
    const float scale = 1.0f / fmaxf(sqrtf(tot), 1e-12f);
    bf16x4 o;
    o[0] = (__bf16)(v.x * scale);
    o[1] = (__bf16)(v.y * scale);
    o[2] = (__bf16)(v.z * scale);
    o[3] = (__bf16)(v.w * scale);
    *(bf16x4*)(xn + (size_t)row * DIM + t * 4) = o;
    if (t == 0) rowmax[row] = 0u;                   // below fkey of any real sim
}

// 256x256 tile of sim = xn*xn^T. Hold-fragment schedule: each of the 24
// unique ds_read_b128 fragments per wave per K-tile is read ONCE; one raw
// s_barrier + vmcnt(0) per K-tile (full 64KB double-buffer => no intra-tile
// cross-wave hazard); stage loads for t+1 spread through tile t; wave drift
// overlaps LDS reads of one wave with MFMAs of another; T2 XOR-swizzle keeps
// ds_reads conflict-free; T5 setprio around MFMA clusters.
__global__ __launch_bounds__(512, 2)
void simmax_kernel(const __hip_bfloat16* __restrict__ xn,
                   unsigned* __restrict__ rowmax) {
    // decode upper-triangle block index -> (it, jt), jt >= it
    int rem = blockIdx.x;
    int it = 0;
    while (rem >= NTILE - it) { rem -= NTILE - it; ++it; }
    const int jt = it + rem;
    const bool diag = (jt == it);
    const int rowBase = it * 256;
    const int colBase = jt * 256;

    __shared__ __hip_bfloat16 lds[2][2][256][64];   // [buf][A/B][row][k] = 128 KiB

    const int t    = threadIdx.x;
    const int lane = t & 63;
    const int wid  = t >> 6;        // 0..7
    const int wr   = wid >> 2;      // 0..1 (M)
    const int wc   = wid & 3;       // 0..3 (N)

    // Staging map: chunk c = l*512 + t  (c<2048: A, else B), row=(c>>3)&255,
    // ch=c&7. LDS dest LINEAR (c*16 B); SOURCE col pre-swizzled (ch ^ (row&7))
    // so the swizzled ds_read finds its data (rule #21).
    const __hip_bfloat16* srcp[8];
#pragma unroll
    for (int l = 0; l < 8; ++l) {
        const int c   = l * 512 + t;
        const int op  = c >> 11;
        const int row = (c >> 3) & 255;
        const int ch  = c & 7;
        const int gr  = (op ? colBase : rowBase) + row;
        const int gc  = (ch ^ (row & 7)) * 8;
        srcp[l] = xn + (size_t)gr * DIM + gc;
    }

    char* ldsb = (char*)&lds[0][0][0][0];

    // prologue: stage K-tile 0 into buf 0 (8 x 16B per thread)
#pragma unroll
    for (int l = 0; l < 8; ++l) {
        __builtin_amdgcn_global_load_lds(
            (const __attribute__((address_space(1))) void*)srcp[l],
            (__attribute__((address_space(3))) void*)(ldsb + (l * 512 + wid * 64) * 16),
            16, 0, 0);
        srcp[l] += 64;
    }

    f32x4 acc[8][4];
#pragma unroll
    for (int m = 0; m < 8; ++m)
#pragma unroll
        for (int n = 0; n < 4; ++n)
            acc[m][n] = (f32x4){0.f, 0.f, 0.f, 0.f};

    const int l15 = lane & 15;
    const int hi  = lane >> 4;

    for (int tk = 0; tk < NT; ++tk) {
        const int cur = tk & 1;
        const bool pf = (tk + 1 < NT);
        char* curA = (char*)&lds[cur][0][0][0];
        char* curB = (char*)&lds[cur][1][0][0];
        char* nxtb = (char*)&lds[cur ^ 1][0][0][0];

        // all 8 stage-loads for THIS tile (issued during tile t-1) must have
        // landed; raw barrier (NOT __syncthreads: that would add lgkmcnt(0)
        // and defeat cross-tile ds pipelining).
        asm volatile("s_waitcnt vmcnt(0)" ::: "memory");
        __builtin_amdgcn_s_barrier();
        __builtin_amdgcn_sched_barrier(0);

        bf16x8 af[4][2], b0[2][2], b1[2][2];
        // A-half 0 (rows wr*128 + 0..63) + both B halves: 16 ds_read_b128
#pragma unroll
        for (int m2 = 0; m2 < 4; ++m2)
#pragma unroll
            for (int kk = 0; kk < 2; ++kk) {
                const int row = wr * 128 + m2 * 16 + l15;
                const int chn = (kk * 4 + hi) ^ (row & 7);
                af[m2][kk] = *(const bf16x8*)(curA + row * 128 + chn * 16);
            }
#pragma unroll
        for (int n2 = 0; n2 < 2; ++n2)
#pragma unroll
            for (int kk = 0; kk < 2; ++kk) {
                const int row = wc * 64 + n2 * 16 + l15;
                const int chn = (kk * 4 + hi) ^ (row & 7);
                b0[n2][kk] = *(const bf16x8*)(curB + row * 128 + chn * 16);
            }
#pragma unroll
        for (int n2 = 0; n2 < 2; ++n2)
#pragma unroll
            for (int kk = 0; kk < 2; ++kk) {
                const int row = wc * 64 + 32 + n2 * 16 + l15;
                const int chn = (kk * 4 + hi) ^ (row & 7);
                b1[n2][kk] = *(const bf16x8*)(curB + row * 128 + chn * 16);
            }
        __builtin_amdgcn_sched_barrier(0);

        // stage first 4 chunks of next tile (writes go to the OTHER buffer)
        if (pf) {
#pragma unroll
            for (int l = 0; l < 4; ++l) {
                __builtin_amdgcn_global_load_lds(
                    (const __attribute__((address_space(1))) void*)srcp[l],
                    (__attribute__((address_space(3))) void*)(nxtb + (l * 512 + wid * 64) * 16),
                    16, 0, 0);
                srcp[l] += 64;
            }
        }
        __builtin_amdgcn_sched_barrier(0);

        // MFMA cluster (0,0): compiler inserts counted lgkm wait (a0+b0 only)
        __builtin_amdgcn_s_setprio(1);
#pragma unroll
        for (int m2 = 0; m2 < 4; ++m2)
#pragma unroll
            for (int n2 = 0; n2 < 2; ++n2)
#pragma unroll
                for (int kk = 0; kk < 2; ++kk)
                    acc[m2][n2] = __builtin_amdgcn_mfma_f32_16x16x32_bf16(
                        af[m2][kk], b0[n2][kk], acc[m2][n2], 0, 0, 0);
        __builtin_amdgcn_s_setprio(0);
        __builtin_amdgcn_sched_barrier(0);

        if (pf) {
#pragma unroll
            for (int l = 4; l < 6; ++l) {
                __builtin_amdgcn_global_load_lds(
                    (const __attribute__((address_space(1))) void*)srcp[l],
                    (__attribute__((address_space(3))) void*)(nxtb + (l * 512 + wid * 64) * 16),
                    16, 0, 0);
                srcp[l] += 64;
            }
        }
        __builtin_amdgcn_sched_barrier(0);

        // MFMA cluster (0,1): b1 drained under cluster (0,0)
        __builtin_amdgcn_s_setprio(1);
#pragma unroll
        for (int m2 = 0; m2 < 4; ++m2)
#pragma unroll
            for (int n2 = 0; n2 < 2; ++n2)
#pragma unroll
                for (int kk = 0; kk < 2; ++kk)
                    acc[m2][n2 + 2] = __builtin_amdgcn_mfma_f32_16x16x32_bf16(
                        af[m2][kk], b1[n2][kk], acc[m2][n2 + 2], 0, 0, 0);
        __builtin_amdgcn_s_setprio(0);
        __builtin_amdgcn_sched_barrier(0);

        // A-half 1 (rows wr*128 + 64..127), reuses af registers (a0 dead)
#pragma unroll
        for (int m2 = 0; m2 < 4; ++m2)
#pragma unroll
            for (int kk = 0; kk < 2; ++kk) {
                const int row = wr * 128 + 64 + m2 * 16 + l15;
                const int chn = (kk * 4 + hi) ^ (row & 7);
                af[m2][kk] = *(const bf16x8*)(curA + row * 128 + chn * 16);
            }
        __builtin_amdgcn_sched_barrier(0);

        if (pf) {
#pragma unroll
            for (int l = 6; l < 8; ++l) {
                __builtin_amdgcn_global_load_lds(
                    (const __attribute__((address_space(1))) void*)srcp[l],
                    (__attribute__((address_space(3))) void*)(nxtb + (l * 512 + wid * 64) * 16),
                    16, 0, 0);
                srcp[l] += 64;
            }
        }
        __builtin_amdgcn_sched_barrier(0);

        // MFMA clusters (1,1) and (1,0)
        __builtin_amdgcn_s_setprio(1);
#pragma unroll
        for (int m2 = 0; m2 < 4; ++m2)
#pragma unroll
            for (int n2 = 0; n2 < 2; ++n2)
#pragma unroll
                for (int kk = 0; kk < 2; ++kk)
                    acc[m2 + 4][n2 + 2] = __builtin_amdgcn_mfma_f32_16x16x32_bf16(
                        af[m2][kk], b1[n2][kk], acc[m2 + 4][n2 + 2], 0, 0, 0);
#pragma unroll
        for (int m2 = 0; m2 < 4; ++m2)
#pragma unroll
            for (int n2 = 0; n2 < 2; ++n2)
#pragma unroll
                for (int kk = 0; kk < 2; ++kk)
                    acc[m2 + 4][n2] = __builtin_amdgcn_mfma_f32_16x16x32_bf16(
                        af[m2][kk], b0[n2][kk], acc[m2 + 4][n2], 0, 0, 0);
        __builtin_amdgcn_s_setprio(0);
        __builtin_amdgcn_sched_barrier(0);
    }

    // ---- epilogue: tile max reduction ----
    // C/D layout: col = lane&15, row = (lane>>4)*4 + reg  [m89/m91]
    const int g  = lane >> 4;
    const int cl = lane & 15;

    if (diag) {                                     // mask self-similarity
#pragma unroll
        for (int m = 0; m < 8; ++m)
#pragma unroll
            for (int n = 0; n < 4; ++n)
#pragma unroll
                for (int r = 0; r < 4; ++r) {
                    const int grow = wr * 128 + m * 16 + g * 4 + r;
                    const int gcol = wc * 64 + n * 16 + cl;
                    if (grow == gcol) acc[m][n][r] = -3.0f;
                }
    }

    // row-direction max (over this tile's cols), reduce over cl lanes
#pragma unroll
    for (int m = 0; m < 8; ++m)
#pragma unroll
        for (int r = 0; r < 4; ++r) {
            float v = fmaxf(fmaxf(acc[m][0][r], acc[m][1][r]),
                            fmaxf(acc[m][2][r], acc[m][3][r]));
            v = fmaxf(v, __shfl_xor(v, 1));
            v = fmaxf(v, __shfl_xor(v, 2));
            v = fmaxf(v, __shfl_xor(v, 4));
            v = fmaxf(v, __shfl_xor(v, 8));
            if (cl == 0) {
                const int grow = rowBase + wr * 128 + m * 16 + g * 4 + r;
                atomicMax(rowmax + grow, fkey(v));
            }
        }

    // col-direction max (transpose contribution), skip on diagonal tiles
    if (!diag) {
#pragma unroll
        for (int n = 0; n < 4; ++n) {
            float v = -3.0f;
#pragma unroll
            for (int m = 0; m < 8; ++m)
#pragma unroll
                for (int r = 0; r < 4; ++r)
                    v = fmaxf(v, acc[m][n][r]);
            v = fmaxf(v, __shfl_xor(v, 16));
            v = fmaxf(v, __shfl_xor(v, 32));
            if (g == 0) {
                const int gcol = colBase + wc * 64 + n * 16 + cl;
                atomicMax(rowmax + gcol, fkey(v));
            }
        }
    }
}

__global__ void finalize_kernel(const unsigned* __restrict__ rowmax,
                                float* __restrict__ out) {
    const int t = threadIdx.x;            // 256 threads, 1 block
    float s = 0.f;
    for (int r = t; r < NROWS; r += 256) {
        const float m = fminf(funkey(rowmax[r]), 1.0f);   // NaN guard
        s += logf(2.0f - 2.0f * m + 1e-8f);
    }
#pragma unroll
    for (int off = 32; off > 0; off >>= 1) s += __shfl_xor(s, off);
    __shared__ float ws[4];
    if ((t & 63) == 0) ws[t >> 6] = s;
    __syncthreads();
    if (t == 0) out[0] = -0.5f * (ws[0] + ws[1] + ws[2] + ws[3]) / (float)NROWS;
}

extern "C" void kernel_launch(void* const* d_in, const int* in_sizes, int n_in,
                              void* d_out, int out_size, void* d_ws, size_t ws_size,
                              hipStream_t stream) {
    const float* x = (const float*)d_in[0];
    __hip_bfloat16* xn = (__hip_bfloat16*)d_ws;
    unsigned* rowmax = (unsigned*)((char*)d_ws + (size_t)NROWS * DIM * sizeof(__hip_bfloat16));
    float* out = (float*)d_out;

    normalize_rows<<<NROWS, 256, 0, stream>>>(x, xn, rowmax);
    simmax_kernel<<<NBLK, 512, 0, stream>>>(xn, rowmax);
    finalize_kernel<<<1, 256, 0, stream>>>(rowmax, out);
}